// Round 3
// baseline (338.038 us; speedup 1.0000x reference)
//
#include <hip/hip_runtime.h>

constexpr int NN    = 100000;   // nodes
constexpr int NNZ_E = 1600000;  // sparse entries
constexpr int EQn   = 200000;   // edges to score
constexpr int INF_  = 256;
constexpr int HIDF  = 128;
constexpr int OUTF  = 64;

typedef float  f32x4  __attribute__((ext_vector_type(4)));
typedef short  bf16x8 __attribute__((ext_vector_type(8)));

// fp32 -> bf16 (round to nearest even)
__device__ inline unsigned short f2bf(float f) {
    union { float f; unsigned int i; } x; x.f = f;
    unsigned int r = x.i + 0x7fffu + ((x.i >> 16) & 1u);
    return (unsigned short)(r >> 16);
}

// async global->LDS, 16 B per lane. LDS dest = wave-uniform base + lane*16.
__device__ inline void gl2lds16(const void* g, void* l) {
    __builtin_amdgcn_global_load_lds(
        (const __attribute__((address_space(1))) void*)g,
        (__attribute__((address_space(3))) void*)l, 16, 0, 0);
}

// ---------------------------------------------------------------------------
// Fused one-shot prep: CSR row_ptr (binary search over sorted rows) and
// W -> Wt bf16 transposes.
// ---------------------------------------------------------------------------
__global__ __launch_bounds__(256) void prep(const int* __restrict__ rows,
                                            int* __restrict__ ptr,
                                            const float* __restrict__ W1,
                                            const float* __restrict__ W2,
                                            unsigned short* __restrict__ W1t,
                                            unsigned short* __restrict__ W2t) {
    int i = blockIdx.x * 256 + threadIdx.x;
    if (i <= NN) {
        int lo = 0, hi = NNZ_E;
        while (lo < hi) {
            int mid = (lo + hi) >> 1;
            if (rows[mid] < i) lo = mid + 1; else hi = mid;
        }
        ptr[i] = lo;
    }
    if (i < INF_ * HIDF) {            // W1 [256][128]
        int k = i >> 7, n = i & 127;
        W1t[n * INF_ + k] = f2bf(W1[i]);
    }
    if (i < HIDF * OUTF) {            // W2 [128][64]
        int k = i >> 6, n = i & 63;
        W2t[n * HIDF + k] = f2bf(W2[i]);
    }
}

// ---------------------------------------------------------------------------
// Per-row edge sort by col (in-wave 64-element bitonic) + pack (col, val)
// into int2. Sorted order gives a monotone sweep over the dense table so
// concurrent rows share an L2-resident window. Rows with >64 edges (never at
// Poisson(16), but handled) are copied unsorted — correctness unaffected.
// Key = (col<<6)|lane: unique keys -> tie-safe compare-exchange.
// ---------------------------------------------------------------------------
__global__ __launch_bounds__(256) void sort_pack(const int* __restrict__ ptr,
                                                 const int* __restrict__ cols,
                                                 const float* __restrict__ vals,
                                                 int2* __restrict__ ep) {
    const int lane = threadIdx.x & 63;
    const int row  = blockIdx.x * 4 + (threadIdx.x >> 6);
    if (row >= NN) return;
    const int e0 = ptr[row], e1 = ptr[row + 1];
    const int n  = e1 - e0;
    if (n <= 0) return;
    if (n <= 64) {
        int key; float v;
        if (lane < n) { key = (cols[e0 + lane] << 6) | lane; v = vals[e0 + lane]; }
        else          { key = 0x7fffff00 | lane;             v = 0.f; }
        #pragma unroll
        for (int k = 2; k <= 64; k <<= 1) {
            #pragma unroll
            for (int j = k >> 1; j > 0; j >>= 1) {
                int   pk_ = __shfl_xor(key, j, 64);
                float pv_ = __shfl_xor(v,   j, 64);
                const bool up    = ((lane & k) == 0);
                const bool lower = ((lane & j) == 0);
                if ((key > pk_) == (lower == up)) { key = pk_; v = pv_; }
            }
        }
        if (lane < n) {
            int2 o; o.x = key >> 6; o.y = __float_as_int(v);
            ep[e0 + lane] = o;
        }
    } else {
        for (int i = lane; i < n; i += 64) {
            int2 o; o.x = cols[e0 + i]; o.y = __float_as_int(vals[e0 + i]);
            ep[e0 + i] = o;
        }
    }
}

// ---------------------------------------------------------------------------
// Persistent-block MFMA GEMM (unchanged from round 0).
// ---------------------------------------------------------------------------
template<int K, int NCOLS, int TR, int CGB, bool A_IS_BF16>
__global__ __launch_bounds__(512, 1) void gemm_persist(const void* __restrict__ Av,
                                                       const unsigned short* __restrict__ Bt,
                                                       const float* __restrict__ bias,
                                                       unsigned short* __restrict__ C,
                                                       int M) {
    constexpr int KS   = K / 32;
    constexpr int NT   = 2;
    constexpr int CG   = 1 << CGB;
    constexpr int RB   = 8 / CG;
    static_assert(RB * 16 == TR, "tile rows = 16*RB");
    static_assert(CG * 32 == NCOLS, "cols = 32*CG");
    constexpr int ABPR = A_IS_BF16 ? K * 2 : K * 4;
    constexpr int RPC  = 1024 / ABPR;
    constexpr int NCH  = TR / RPC;
    constexpr int CPWW = NCH / 8;
    constexpr int ABUF = NCH * 1040;
    constexpr int PK   = K + 8;
    constexpr int PADW = NCOLS + 8;
    constexpr int BSB  = NCOLS * PK * 2;
    constexpr int EPB  = TR * PADW * 2;
    static_assert(TR * NCOLS / 8 == 512, "one uint4 store per thread");
    __shared__ __align__(16) unsigned char smem[2 * ABUF + BSB + EPB];
    unsigned char*  Ab = smem;
    unsigned short* Bs = (unsigned short*)(smem + 2 * ABUF);
    unsigned short* ep = (unsigned short*)(smem + 2 * ABUF + BSB);

    const int tid  = threadIdx.x;
    const int wave = tid >> 6;
    const int lane = tid & 63;
    const int quad = lane >> 4;
    const int l16  = lane & 15;
    const int cg   = wave & (CG - 1);
    const int rb   = wave >> CGB;

    for (int i = tid; i < NCOLS * K / 8; i += 512) {
        int n = i / (K / 8), kc = (i % (K / 8)) * 8;
        *(uint4*)&Bs[n * PK + kc] = *(const uint4*)&Bt[(size_t)n * K + kc];
    }

    const int ntiles = (M + TR - 1) / TR;
    const char* abase = (const char*)Av;

    auto stage = [&](int b, int tile0) {
        unsigned char* dst = Ab + b * ABUF;
        #pragma unroll
        for (int j = 0; j < CPWW; ++j) {
            int ch = wave * CPWW + j;
            int r0 = tile0 + ch * RPC;
            if (r0 > M - RPC) r0 = M - RPC;
            gl2lds16(abase + (size_t)r0 * ABPR + lane * 16, dst + ch * 1040);
        }
    };

    int t = blockIdx.x, buf = 0;
    if (t < ntiles) stage(0, t * TR);

    for (; t < ntiles; t += gridDim.x) {
        __syncthreads();
        int tn = t + gridDim.x;
        if (tn < ntiles) stage(1 - buf, tn * TR);

        const unsigned char* ab = Ab + buf * ABUF;
        const int arow = rb * 16 + l16;
        f32x4 acc[NT];
        #pragma unroll
        for (int tt = 0; tt < NT; ++tt) acc[tt] = (f32x4){0.f, 0.f, 0.f, 0.f};

        #pragma unroll
        for (int ks = 0; ks < KS; ++ks) {
            bf16x8 af;
            if constexpr (A_IS_BF16) {
                int flat = arow * ABPR + ks * 64 + quad * 16;
                af = *(const bf16x8*)(ab + (flat >> 10) * 1040 + (flat & 1023));
            } else {
                int flat = arow * ABPR + ks * 128 + quad * 32;
                const unsigned char* p = ab + (flat >> 10) * 1040 + (flat & 1023);
                float4 a0 = *(const float4*)p;
                float4 a1 = *(const float4*)(p + 16);
                af[0] = (short)f2bf(a0.x); af[1] = (short)f2bf(a0.y);
                af[2] = (short)f2bf(a0.z); af[3] = (short)f2bf(a0.w);
                af[4] = (short)f2bf(a1.x); af[5] = (short)f2bf(a1.y);
                af[6] = (short)f2bf(a1.z); af[7] = (short)f2bf(a1.w);
            }
            #pragma unroll
            for (int tt = 0; tt < NT; ++tt) {
                bf16x8 bfr = *(const bf16x8*)&Bs[(cg * 32 + tt * 16 + l16) * PK + ks * 32 + quad * 8];
                acc[tt] = __builtin_amdgcn_mfma_f32_16x16x32_bf16(af, bfr, acc[tt], 0, 0, 0);
            }
        }

        #pragma unroll
        for (int tt = 0; tt < NT; ++tt) {
            const int col = cg * 32 + tt * 16 + l16;
            const float bb = bias[col];
            #pragma unroll
            for (int r = 0; r < 4; ++r)
                ep[(rb * 16 + quad * 4 + r) * PADW + col] = f2bf(acc[tt][r] + bb);
        }
        __syncthreads();
        {
            constexpr int CH = NCOLS / 8;
            int r = tid / CH, cc = tid % CH;
            int grow = t * TR + r;
            if (grow < M)
                *(uint4*)&C[(size_t)grow * NCOLS + cc * 8] =
                    *(const uint4*)&ep[r * PADW + cc * 8];
        }
        buf ^= 1;
    }
}

// ---------------------------------------------------------------------------
// Row-parallel CSR SpMM over col-sorted packed edges, PERSISTENT grid.
// Persistent launch keeps all resident rows phase-aligned in their sorted
// sweep over the dense table -> instantaneous working set is a moving window
// (few MB) instead of the whole table -> L2 hits instead of L3/HBM fetches.
// 16 lanes/row @ D=128 (uint4 = 256B/row/instr), 8 @ D=64.
// 4-edge padded batches (clamp idx, val=0): no scalar tail.
// ---------------------------------------------------------------------------
__device__ inline void fma8_bf16(float* acc, uint4 q, float v) {
    union { unsigned int i; float f; } t;
    #pragma unroll
    for (int p = 0; p < 4; ++p) {
        unsigned int w = (&q.x)[p];
        t.i = w << 16;          acc[2*p]   += v * t.f;
        t.i = w & 0xffff0000u;  acc[2*p+1] += v * t.f;
    }
}

template<int D, bool RELU>
__global__ __launch_bounds__(256) void spmm_sw(const int* __restrict__ ptr,
                                               const int2* __restrict__ ep,
                                               const unsigned short* __restrict__ dense,
                                               unsigned short* __restrict__ outm) {
    constexpr int LPR = D / 8;       // lanes per row
    constexpr int RPB = 256 / LPR;   // rows per block-iteration
    constexpr int NRG = (NN + RPB - 1) / RPB;
    const int lane = threadIdx.x % LPR;
    const int rl   = threadIdx.x / LPR;
    const size_t lo8 = (size_t)lane * 8;

    for (int rg = blockIdx.x; rg < NRG; rg += gridDim.x) {
        const int row = rg * RPB + rl;
        if (row >= NN) continue;

        int e = ptr[row];
        const int e1 = ptr[row + 1];
        float acc[8] = {};

        if (e < e1) {
            for (; e + 4 <= e1; e += 4) {
                int2 p0 = ep[e], p1 = ep[e+1], p2 = ep[e+2], p3 = ep[e+3];
                uint4 q0 = *(const uint4*)&dense[(size_t)p0.x * D + lo8];
                uint4 q1 = *(const uint4*)&dense[(size_t)p1.x * D + lo8];
                uint4 q2 = *(const uint4*)&dense[(size_t)p2.x * D + lo8];
                uint4 q3 = *(const uint4*)&dense[(size_t)p3.x * D + lo8];
                fma8_bf16(acc, q0, __int_as_float(p0.y));
                fma8_bf16(acc, q1, __int_as_float(p1.y));
                fma8_bf16(acc, q2, __int_as_float(p2.y));
                fma8_bf16(acc, q3, __int_as_float(p3.y));
            }
            if (e < e1) {   // padded final batch: clamp index, zero value
                int i1 = e, i2 = e + 1, i3 = e + 2;
                bool k1 = i1 < e1, k2 = i2 < e1, k3 = i3 < e1;
                i1 = k1 ? i1 : e1 - 1; i2 = k2 ? i2 : e1 - 1; i3 = k3 ? i3 : e1 - 1;
                int2 p0 = ep[i1], p1 = ep[i2], p2 = ep[i3];
                float v0 = k1 ? __int_as_float(p0.y) : 0.f;
                float v1 = k2 ? __int_as_float(p1.y) : 0.f;
                float v2 = k3 ? __int_as_float(p2.y) : 0.f;
                uint4 q0 = *(const uint4*)&dense[(size_t)p0.x * D + lo8];
                uint4 q1 = *(const uint4*)&dense[(size_t)p1.x * D + lo8];
                uint4 q2 = *(const uint4*)&dense[(size_t)p2.x * D + lo8];
                fma8_bf16(acc, q0, v0);
                fma8_bf16(acc, q1, v1);
                fma8_bf16(acc, q2, v2);
            }
        }

        if (RELU) {
            #pragma unroll
            for (int p = 0; p < 8; ++p) acc[p] = fmaxf(acc[p], 0.f);
        }
        uint4 o;
        #pragma unroll
        for (int p = 0; p < 4; ++p)
            (&o.x)[p] = (unsigned int)f2bf(acc[2*p]) | ((unsigned int)f2bf(acc[2*p+1]) << 16);
        *(uint4*)&outm[(size_t)row * D + lo8] = o;
    }
}

// ---------------------------------------------------------------------------
// Decode: out[e] = dot(z[src[e]], z[dst[e]]), z bf16 [N,64]. 8 lanes/edge,
// 2 edges per lane-group -> 4 independent gathers in flight.
// ---------------------------------------------------------------------------
__global__ __launch_bounds__(256) void decode_dot_bf16(const unsigned short* __restrict__ z,
                                                       const int* __restrict__ ei,
                                                       float* __restrict__ outv) {
    constexpr int HALF = EQn / 2;
    const int lane = threadIdx.x & 7;
    const int g    = blockIdx.x * 32 + (threadIdx.x >> 3);
    if (g >= HALF) return;
    const int eA = g, eB = g + HALF;
    const int sA = ei[eA],       dA = ei[EQn + eA];
    const int sB = ei[eB],       dB = ei[EQn + eB];
    uint4 qa0 = *(const uint4*)&z[(size_t)sA * 64 + lane * 8];
    uint4 qb0 = *(const uint4*)&z[(size_t)dA * 64 + lane * 8];
    uint4 qa1 = *(const uint4*)&z[(size_t)sB * 64 + lane * 8];
    uint4 qb1 = *(const uint4*)&z[(size_t)dB * 64 + lane * 8];
    union { unsigned int i; float f; } ta, tb;
    float p0 = 0.f, p1 = 0.f;
    #pragma unroll
    for (int k = 0; k < 4; ++k) {
        unsigned int wa = (&qa0.x)[k], wb = (&qb0.x)[k];
        ta.i = wa << 16;         tb.i = wb << 16;         p0 += ta.f * tb.f;
        ta.i = wa & 0xffff0000u; tb.i = wb & 0xffff0000u; p0 += ta.f * tb.f;
        wa = (&qa1.x)[k]; wb = (&qb1.x)[k];
        ta.i = wa << 16;         tb.i = wb << 16;         p1 += ta.f * tb.f;
        ta.i = wa & 0xffff0000u; tb.i = wb & 0xffff0000u; p1 += ta.f * tb.f;
    }
    p0 += __shfl_xor(p0, 1, 8); p1 += __shfl_xor(p1, 1, 8);
    p0 += __shfl_xor(p0, 2, 8); p1 += __shfl_xor(p1, 2, 8);
    p0 += __shfl_xor(p0, 4, 8); p1 += __shfl_xor(p1, 4, 8);
    if (lane == 0) { outv[eA] = p0; outv[eB] = p1; }
}

// ---------------------------------------------------------------------------
extern "C" void kernel_launch(void* const* d_in, const int* in_sizes, int n_in,
                              void* d_out, int out_size, void* d_ws, size_t ws_size,
                              hipStream_t stream) {
    (void)in_sizes; (void)n_in; (void)out_size; (void)ws_size;

    const float* x        = (const float*)d_in[0];
    const int*   adj_rows = (const int*)  d_in[1];
    const int*   adj_cols = (const int*)  d_in[2];
    const float* adj_vals = (const float*)d_in[3];
    const int*   ei       = (const int*)  d_in[4];   // [2, EQ]
    const float* W1       = (const float*)d_in[5];
    const float* b1       = (const float*)d_in[6];
    const float* W2       = (const float*)d_in[7];
    const float* b2       = (const float*)d_in[8];
    float* out = (float*)d_out;

    // workspace: row_ptr | W1t | W2t | slotA bf16 [N,128] | slotB bf16 [N,128]
    //            | packed sorted edges int2 [NNZ]
    char* ws = (char*)d_ws;
    int* row_ptr = (int*)ws;
    size_t off = ((size_t)(NN + 1) * sizeof(int) + 511) & ~(size_t)511;
    unsigned short* W1t = (unsigned short*)(ws + off);              // 64 KB
    unsigned short* W2t = W1t + (size_t)HIDF * INF_;                // 16 KB
    unsigned short* slotA = W2t + (size_t)OUTF * HIDF;
    slotA = (unsigned short*)(((size_t)slotA + 511) & ~(size_t)511);
    unsigned short* slotB = slotA + (size_t)NN * HIDF;
    int2* epk = (int2*)(((size_t)(slotB + (size_t)NN * HIDF) + 511) & ~(size_t)511);

    prep<<<(NN + 256) / 256, 256, 0, stream>>>(adj_rows, row_ptr, W1, W2, W1t, W2t);

    // per-row col-sort + pack (enables sweep locality in both spmms)
    sort_pack<<<(NN + 3) / 4, 256, 0, stream>>>(row_ptr, adj_cols, adj_vals, epk);

    // h0 = x @ W1 + b1  -> slotA bf16 [N,128]   (persistent: ~1 block/CU)
    gemm_persist<INF_, HIDF, 32, 2, false><<<256, 512, 0, stream>>>(
        x, W1t, b1, slotA, NN);

    // h = relu(spmm(h0)) -> slotB bf16 [N,128]  (persistent sorted sweep)
    spmm_sw<HIDF, true><<<2048, 256, 0, stream>>>(
        row_ptr, epk, slotA, slotB);

    // z0 = h @ W2 + b2 -> slotA bf16 [N,64]  (A bf16; 2 blocks/CU)
    gemm_persist<HIDF, OUTF, 64, 1, true><<<512, 512, 0, stream>>>(
        slotB, W2t, b2, slotA, NN);

    // z = spmm(z0) -> slotB bf16 [N,64]
    spmm_sw<OUTF, false><<<2048, 256, 0, stream>>>(
        row_ptr, epk, slotA, slotB);

    // out[e] = dot(z[src], z[dst])
    decode_dot_bf16<<<(EQn / 2) / 32, 256, 0, stream>>>(slotB, ei, out);
}

// Round 4
// 285.695 us; speedup vs baseline: 1.1832x; 1.1832x over previous
//
#include <hip/hip_runtime.h>

constexpr int NN    = 100000;   // nodes
constexpr int NNZ_E = 1600000;  // sparse entries
constexpr int EQn   = 200000;   // edges to score
constexpr int INF_  = 256;
constexpr int HIDF  = 128;
constexpr int OUTF  = 64;

typedef float  f32x4  __attribute__((ext_vector_type(4)));
typedef short  bf16x8 __attribute__((ext_vector_type(8)));

// fp32 -> bf16 (round to nearest even)
__device__ inline unsigned short f2bf(float f) {
    union { float f; unsigned int i; } x; x.f = f;
    unsigned int r = x.i + 0x7fffu + ((x.i >> 16) & 1u);
    return (unsigned short)(r >> 16);
}

// async global->LDS, 16 B per lane. LDS dest = wave-uniform base + lane*16.
__device__ inline void gl2lds16(const void* g, void* l) {
    __builtin_amdgcn_global_load_lds(
        (const __attribute__((address_space(1))) void*)g,
        (__attribute__((address_space(3))) void*)l, 16, 0, 0);
}

// ---------------------------------------------------------------------------
// Fused one-shot prep: CSR row_ptr (binary search over sorted rows) and
// W -> Wt bf16 transposes.
// ---------------------------------------------------------------------------
__global__ __launch_bounds__(256) void prep(const int* __restrict__ rows,
                                            int* __restrict__ ptr,
                                            const float* __restrict__ W1,
                                            const float* __restrict__ W2,
                                            unsigned short* __restrict__ W1t,
                                            unsigned short* __restrict__ W2t) {
    int i = blockIdx.x * 256 + threadIdx.x;
    if (i <= NN) {
        int lo = 0, hi = NNZ_E;
        while (lo < hi) {
            int mid = (lo + hi) >> 1;
            if (rows[mid] < i) lo = mid + 1; else hi = mid;
        }
        ptr[i] = lo;
    }
    if (i < INF_ * HIDF) {            // W1 [256][128]
        int k = i >> 7, n = i & 127;
        W1t[n * INF_ + k] = f2bf(W1[i]);
    }
    if (i < HIDF * OUTF) {            // W2 [128][64]
        int k = i >> 6, n = i & 63;
        W2t[n * HIDF + k] = f2bf(W2[i]);
    }
}

// ---------------------------------------------------------------------------
// Persistent-block MFMA GEMM (layer 1 only).
// ---------------------------------------------------------------------------
template<int K, int NCOLS, int TR, int CGB, bool A_IS_BF16>
__global__ __launch_bounds__(512, 1) void gemm_persist(const void* __restrict__ Av,
                                                       const unsigned short* __restrict__ Bt,
                                                       const float* __restrict__ bias,
                                                       unsigned short* __restrict__ C,
                                                       int M) {
    constexpr int KS   = K / 32;
    constexpr int NT   = 2;
    constexpr int CG   = 1 << CGB;
    constexpr int RB   = 8 / CG;
    static_assert(RB * 16 == TR, "tile rows = 16*RB");
    static_assert(CG * 32 == NCOLS, "cols = 32*CG");
    constexpr int ABPR = A_IS_BF16 ? K * 2 : K * 4;
    constexpr int RPC  = 1024 / ABPR;
    constexpr int NCH  = TR / RPC;
    constexpr int CPWW = NCH / 8;
    constexpr int ABUF = NCH * 1040;
    constexpr int PK   = K + 8;
    constexpr int PADW = NCOLS + 8;
    constexpr int BSB  = NCOLS * PK * 2;
    constexpr int EPB  = TR * PADW * 2;
    static_assert(TR * NCOLS / 8 == 512, "one uint4 store per thread");
    __shared__ __align__(16) unsigned char smem[2 * ABUF + BSB + EPB];
    unsigned char*  Ab = smem;
    unsigned short* Bs = (unsigned short*)(smem + 2 * ABUF);
    unsigned short* ep = (unsigned short*)(smem + 2 * ABUF + BSB);

    const int tid  = threadIdx.x;
    const int wave = tid >> 6;
    const int lane = tid & 63;
    const int quad = lane >> 4;
    const int l16  = lane & 15;
    const int cg   = wave & (CG - 1);
    const int rb   = wave >> CGB;

    for (int i = tid; i < NCOLS * K / 8; i += 512) {
        int n = i / (K / 8), kc = (i % (K / 8)) * 8;
        *(uint4*)&Bs[n * PK + kc] = *(const uint4*)&Bt[(size_t)n * K + kc];
    }

    const int ntiles = (M + TR - 1) / TR;
    const char* abase = (const char*)Av;

    auto stage = [&](int b, int tile0) {
        unsigned char* dst = Ab + b * ABUF;
        #pragma unroll
        for (int j = 0; j < CPWW; ++j) {
            int ch = wave * CPWW + j;
            int r0 = tile0 + ch * RPC;
            if (r0 > M - RPC) r0 = M - RPC;
            gl2lds16(abase + (size_t)r0 * ABPR + lane * 16, dst + ch * 1040);
        }
    };

    int t = blockIdx.x, buf = 0;
    if (t < ntiles) stage(0, t * TR);

    for (; t < ntiles; t += gridDim.x) {
        __syncthreads();
        int tn = t + gridDim.x;
        if (tn < ntiles) stage(1 - buf, tn * TR);

        const unsigned char* ab = Ab + buf * ABUF;
        const int arow = rb * 16 + l16;
        f32x4 acc[NT];
        #pragma unroll
        for (int tt = 0; tt < NT; ++tt) acc[tt] = (f32x4){0.f, 0.f, 0.f, 0.f};

        #pragma unroll
        for (int ks = 0; ks < KS; ++ks) {
            bf16x8 af;
            if constexpr (A_IS_BF16) {
                int flat = arow * ABPR + ks * 64 + quad * 16;
                af = *(const bf16x8*)(ab + (flat >> 10) * 1040 + (flat & 1023));
            } else {
                int flat = arow * ABPR + ks * 128 + quad * 32;
                const unsigned char* p = ab + (flat >> 10) * 1040 + (flat & 1023);
                float4 a0 = *(const float4*)p;
                float4 a1 = *(const float4*)(p + 16);
                af[0] = (short)f2bf(a0.x); af[1] = (short)f2bf(a0.y);
                af[2] = (short)f2bf(a0.z); af[3] = (short)f2bf(a0.w);
                af[4] = (short)f2bf(a1.x); af[5] = (short)f2bf(a1.y);
                af[6] = (short)f2bf(a1.z); af[7] = (short)f2bf(a1.w);
            }
            #pragma unroll
            for (int tt = 0; tt < NT; ++tt) {
                bf16x8 bfr = *(const bf16x8*)&Bs[(cg * 32 + tt * 16 + l16) * PK + ks * 32 + quad * 8];
                acc[tt] = __builtin_amdgcn_mfma_f32_16x16x32_bf16(af, bfr, acc[tt], 0, 0, 0);
            }
        }

        #pragma unroll
        for (int tt = 0; tt < NT; ++tt) {
            const int col = cg * 32 + tt * 16 + l16;
            const float bb = bias[col];
            #pragma unroll
            for (int r = 0; r < 4; ++r)
                ep[(rb * 16 + quad * 4 + r) * PADW + col] = f2bf(acc[tt][r] + bb);
        }
        __syncthreads();
        {
            constexpr int CH = NCOLS / 8;
            int r = tid / CH, cc = tid % CH;
            int grow = t * TR + r;
            if (grow < M)
                *(uint4*)&C[(size_t)grow * NCOLS + cc * 8] =
                    *(const uint4*)&ep[r * PADW + cc * 8];
        }
        buf ^= 1;
    }
}

// ---------------------------------------------------------------------------
// Shared gather helper (round-0 proven shape).
// ---------------------------------------------------------------------------
__device__ inline void fma8_bf16(float* acc, uint4 q, float v) {
    union { unsigned int i; float f; } t;
    #pragma unroll
    for (int p = 0; p < 4; ++p) {
        unsigned int w = (&q.x)[p];
        t.i = w << 16;          acc[2*p]   += v * t.f;
        t.i = w & 0xffff0000u;  acc[2*p+1] += v * t.f;
    }
}

template<int D>
__device__ inline void spmm_row_accum(int e, int e1,
                                      const int* __restrict__ cols,
                                      const float* __restrict__ vals,
                                      const unsigned short* __restrict__ dense,
                                      size_t lo8, float* acc) {
    if (e >= e1) return;
    for (; e + 4 <= e1; e += 4) {
        int   c0 = cols[e],   c1 = cols[e+1], c2 = cols[e+2], c3 = cols[e+3];
        float v0 = vals[e],   v1 = vals[e+1], v2 = vals[e+2], v3 = vals[e+3];
        uint4 q0 = *(const uint4*)&dense[(size_t)c0 * D + lo8];
        uint4 q1 = *(const uint4*)&dense[(size_t)c1 * D + lo8];
        uint4 q2 = *(const uint4*)&dense[(size_t)c2 * D + lo8];
        uint4 q3 = *(const uint4*)&dense[(size_t)c3 * D + lo8];
        fma8_bf16(acc, q0, v0);
        fma8_bf16(acc, q1, v1);
        fma8_bf16(acc, q2, v2);
        fma8_bf16(acc, q3, v3);
    }
    if (e < e1) {   // padded final batch: clamp index, zero value
        int i1 = e, i2 = e + 1, i3 = e + 2;
        bool k1 = i1 < e1, k2 = i2 < e1, k3 = i3 < e1;
        i1 = k1 ? i1 : e1 - 1; i2 = k2 ? i2 : e1 - 1; i3 = k3 ? i3 : e1 - 1;
        int   c0 = cols[i1],            c1 = cols[i2],            c2 = cols[i3];
        float v0 = k1 ? vals[i1] : 0.f, v1 = k2 ? vals[i2] : 0.f, v2 = k3 ? vals[i3] : 0.f;
        uint4 q0 = *(const uint4*)&dense[(size_t)c0 * D + lo8];
        uint4 q1 = *(const uint4*)&dense[(size_t)c1 * D + lo8];
        uint4 q2 = *(const uint4*)&dense[(size_t)c2 * D + lo8];
        fma8_bf16(acc, q0, v0);
        fma8_bf16(acc, q1, v1);
        fma8_bf16(acc, q2, v2);
    }
}

// ---------------------------------------------------------------------------
// FUSED: h = relu(spmm(h0)); z0 = h @ W2 + b2  -> bf16 [N,64], one kernel.
// Block = 256 threads = 16 rows x 16 lanes (D=128 gather, round-0 shape).
// Epilogue: stage 16x128 h-tile + padded W2 in LDS, 4 waves x 4 MFMAs
// produce the 16x64 z0 tile. Eliminates gemm2's dispatch + 38.4 MB traffic
// and halves this kernel's write (25.6 -> 12.8 MB).
// Rows with no edges naturally yield z0 = b2 (h row = 0), same as unfused.
// ---------------------------------------------------------------------------
__global__ __launch_bounds__(256) void spmm1_fused(const int* __restrict__ ptr,
                                                   const int* __restrict__ cols,
                                                   const float* __restrict__ vals,
                                                   const unsigned short* __restrict__ dense, // h0 [N,128]
                                                   const unsigned short* __restrict__ W2t,   // [64][128]
                                                   const float* __restrict__ b2,
                                                   unsigned short* __restrict__ z0) {        // [N,64]
    constexpr int D = 128;
    static_assert(NN % 16 == 0, "exact tiling, no tail guard");
    // padded rows (+8 elems = 16B) -> MFMA b128 LDS reads are ~2-way, free
    __shared__ __align__(16) unsigned short W2s[64 * 136];
    __shared__ __align__(16) unsigned short ht[16 * 136];
    __shared__ __align__(16) unsigned short zt[16 * 72];

    const int tid = threadIdx.x;

    // stage W2 into padded LDS (16 KB from L2; hot after first blocks)
    #pragma unroll
    for (int i = 0; i < 4; ++i) {
        int idx = tid + i * 256;            // 1024 uint4 chunks total
        int r = idx >> 4, ch = idx & 15;
        *(uint4*)&W2s[r * 136 + ch * 8] = *(const uint4*)&W2t[r * 128 + ch * 8];
    }

    // ---- gather phase (identical inner loop to round-0 spmm) ----
    const int lane16 = tid & 15;
    const int rl     = tid >> 4;
    const int row    = blockIdx.x * 16 + rl;
    const size_t lo8 = (size_t)lane16 * 8;
    float acc[8] = {};
    spmm_row_accum<D>(ptr[row], ptr[row + 1], cols, vals, dense, lo8, acc);

    uint4 o;
    #pragma unroll
    for (int p = 0; p < 4; ++p) {
        float a0 = fmaxf(acc[2*p],   0.f);
        float a1 = fmaxf(acc[2*p+1], 0.f);
        (&o.x)[p] = (unsigned int)f2bf(a0) | ((unsigned int)f2bf(a1) << 16);
    }
    *(uint4*)&ht[rl * 136 + lane16 * 8] = o;
    __syncthreads();

    // ---- MFMA epilogue: z0 tile = ht(16x128) @ W2(128x64) ----
    const int wv   = tid >> 6;       // wave -> output col block wv*16
    const int lane = tid & 63;
    const int l16  = lane & 15;
    const int quad = lane >> 4;
    f32x4 c = (f32x4){0.f, 0.f, 0.f, 0.f};
    #pragma unroll
    for (int ks = 0; ks < 4; ++ks) {
        bf16x8 af = *(const bf16x8*)&ht[l16 * 136 + ks * 32 + quad * 8];
        bf16x8 bf_ = *(const bf16x8*)&W2s[(wv * 16 + l16) * 136 + ks * 32 + quad * 8];
        c = __builtin_amdgcn_mfma_f32_16x16x32_bf16(af, bf_, c, 0, 0, 0);
    }
    const float bb = b2[wv * 16 + l16];
    #pragma unroll
    for (int r = 0; r < 4; ++r)
        zt[(quad * 4 + r) * 72 + wv * 16 + l16] = f2bf(c[r] + bb);
    __syncthreads();

    // coalesced store: 16 rows x 64 cols bf16 = 128 uint4
    if (tid < 128) {
        int r = tid >> 3, cc = tid & 7;
        *(uint4*)&z0[((size_t)blockIdx.x * 16 + r) * 64 + cc * 8] =
            *(const uint4*)&zt[r * 72 + cc * 8];
    }
}

// ---------------------------------------------------------------------------
// Plain SpMM (layer 2, D=64): round-0 proven kernel.
// ---------------------------------------------------------------------------
template<int D, bool RELU>
__global__ __launch_bounds__(256) void spmm_bf16(const int* __restrict__ ptr,
                                                 const int* __restrict__ cols,
                                                 const float* __restrict__ vals,
                                                 const unsigned short* __restrict__ dense,
                                                 unsigned short* __restrict__ outm) {
    constexpr int LPR = D / 8;       // lanes per row
    constexpr int RPB = 256 / LPR;   // rows per block
    const int lane = threadIdx.x % LPR;
    const int row  = blockIdx.x * RPB + threadIdx.x / LPR;
    if (row >= NN) return;

    const size_t lo8 = (size_t)lane * 8;
    float acc[8] = {};
    spmm_row_accum<D>(ptr[row], ptr[row + 1], cols, vals, dense, lo8, acc);

    if (RELU) {
        #pragma unroll
        for (int p = 0; p < 8; ++p) acc[p] = fmaxf(acc[p], 0.f);
    }
    uint4 o;
    #pragma unroll
    for (int p = 0; p < 4; ++p)
        (&o.x)[p] = (unsigned int)f2bf(acc[2*p]) | ((unsigned int)f2bf(acc[2*p+1]) << 16);
    *(uint4*)&outm[(size_t)row * D + lo8] = o;
}

// ---------------------------------------------------------------------------
// Decode: out[e] = dot(z[src[e]], z[dst[e]]), z bf16 [N,64]. 8 lanes/edge,
// 2 edges per lane-group -> 4 independent gathers in flight.
// ---------------------------------------------------------------------------
__global__ __launch_bounds__(256) void decode_dot_bf16(const unsigned short* __restrict__ z,
                                                       const int* __restrict__ ei,
                                                       float* __restrict__ outv) {
    constexpr int HALF = EQn / 2;
    const int lane = threadIdx.x & 7;
    const int g    = blockIdx.x * 32 + (threadIdx.x >> 3);
    if (g >= HALF) return;
    const int eA = g, eB = g + HALF;
    const int sA = ei[eA],       dA = ei[EQn + eA];
    const int sB = ei[eB],       dB = ei[EQn + eB];
    uint4 qa0 = *(const uint4*)&z[(size_t)sA * 64 + lane * 8];
    uint4 qb0 = *(const uint4*)&z[(size_t)dA * 64 + lane * 8];
    uint4 qa1 = *(const uint4*)&z[(size_t)sB * 64 + lane * 8];
    uint4 qb1 = *(const uint4*)&z[(size_t)dB * 64 + lane * 8];
    union { unsigned int i; float f; } ta, tb;
    float p0 = 0.f, p1 = 0.f;
    #pragma unroll
    for (int k = 0; k < 4; ++k) {
        unsigned int wa = (&qa0.x)[k], wb = (&qb0.x)[k];
        ta.i = wa << 16;         tb.i = wb << 16;         p0 += ta.f * tb.f;
        ta.i = wa & 0xffff0000u; tb.i = wb & 0xffff0000u; p0 += ta.f * tb.f;
        wa = (&qa1.x)[k]; wb = (&qb1.x)[k];
        ta.i = wa << 16;         tb.i = wb << 16;         p1 += ta.f * tb.f;
        ta.i = wa & 0xffff0000u; tb.i = wb & 0xffff0000u; p1 += ta.f * tb.f;
    }
    p0 += __shfl_xor(p0, 1, 8); p1 += __shfl_xor(p1, 1, 8);
    p0 += __shfl_xor(p0, 2, 8); p1 += __shfl_xor(p1, 2, 8);
    p0 += __shfl_xor(p0, 4, 8); p1 += __shfl_xor(p1, 4, 8);
    if (lane == 0) { outv[eA] = p0; outv[eB] = p1; }
}

// ---------------------------------------------------------------------------
extern "C" void kernel_launch(void* const* d_in, const int* in_sizes, int n_in,
                              void* d_out, int out_size, void* d_ws, size_t ws_size,
                              hipStream_t stream) {
    (void)in_sizes; (void)n_in; (void)out_size; (void)ws_size;

    const float* x        = (const float*)d_in[0];
    const int*   adj_rows = (const int*)  d_in[1];
    const int*   adj_cols = (const int*)  d_in[2];
    const float* adj_vals = (const float*)d_in[3];
    const int*   ei       = (const int*)  d_in[4];   // [2, EQ]
    const float* W1       = (const float*)d_in[5];
    const float* b1       = (const float*)d_in[6];
    const float* W2       = (const float*)d_in[7];
    const float* b2       = (const float*)d_in[8];
    float* out = (float*)d_out;

    // workspace: row_ptr | W1t | W2t | slotA bf16 [N,128] | slotB bf16 [N,128]
    char* ws = (char*)d_ws;
    int* row_ptr = (int*)ws;
    size_t off = ((size_t)(NN + 1) * sizeof(int) + 511) & ~(size_t)511;
    unsigned short* W1t = (unsigned short*)(ws + off);              // 64 KB
    unsigned short* W2t = W1t + (size_t)HIDF * INF_;                // 16 KB
    unsigned short* slotA = W2t + (size_t)OUTF * HIDF;
    slotA = (unsigned short*)(((size_t)slotA + 511) & ~(size_t)511);
    unsigned short* slotB = slotA + (size_t)NN * HIDF;

    prep<<<(NN + 256) / 256, 256, 0, stream>>>(adj_rows, row_ptr, W1, W2, W1t, W2t);

    // h0 = x @ W1 + b1  -> slotA bf16 [N,128]   (persistent: ~1 block/CU)
    gemm_persist<INF_, HIDF, 32, 2, false><<<256, 512, 0, stream>>>(
        x, W1t, b1, slotA, NN);

    // z0 = relu(spmm(h0)) @ W2 + b2 -> slotB bf16 [N,64]   (FUSED)
    spmm1_fused<<<NN / 16, 256, 0, stream>>>(
        row_ptr, adj_cols, adj_vals, slotA, W2t, b2, slotB);

    // z = spmm(z0) -> slotA bf16 [N,64]
    spmm_bf16<OUTF, false><<<(NN + 31) / 32, 256, 0, stream>>>(
        row_ptr, adj_cols, adj_vals, slotB, slotA);

    // out[e] = dot(z[src], z[dst])
    decode_dot_bf16<<<(EQn / 2) / 32, 256, 0, stream>>>(slotA, ei, out);
}

// Round 5
// 280.516 us; speedup vs baseline: 1.2051x; 1.0185x over previous
//
#include <hip/hip_runtime.h>

constexpr int NN    = 100000;   // nodes
constexpr int NNZ_E = 1600000;  // sparse entries
constexpr int EQn   = 200000;   // edges to score
constexpr int INF_  = 256;
constexpr int HIDF  = 128;
constexpr int OUTF  = 64;

typedef float  f32x4  __attribute__((ext_vector_type(4)));
typedef short  bf16x8 __attribute__((ext_vector_type(8)));

// fp32 -> bf16 (round to nearest even)
__device__ inline unsigned short f2bf(float f) {
    union { float f; unsigned int i; } x; x.f = f;
    unsigned int r = x.i + 0x7fffu + ((x.i >> 16) & 1u);
    return (unsigned short)(r >> 16);
}

// async global->LDS, 16 B per lane. LDS dest = wave-uniform base + lane*16.
__device__ inline void gl2lds16(const void* g, void* l) {
    __builtin_amdgcn_global_load_lds(
        (const __attribute__((address_space(1))) void*)g,
        (__attribute__((address_space(3))) void*)l, 16, 0, 0);
}

// ---------------------------------------------------------------------------
// Prep v2: row_ptr by BOUNDARY SCAN (rows is sorted — thread e marks the
// boundary range rows[e-1] < r <= rows[e]; avg 0.0625 writes/thread), plus
// W -> Wt bf16 transposes in the same dispatch. Replaces 100k x 21 dependent
// random probes (latency chain) with 2 coalesced sweeps of rows[].
// ---------------------------------------------------------------------------
__global__ __launch_bounds__(256) void prep(const int* __restrict__ rows,
                                            int* __restrict__ ptr,
                                            const float* __restrict__ W1,
                                            const float* __restrict__ W2,
                                            unsigned short* __restrict__ W1t,
                                            unsigned short* __restrict__ W2t) {
    const int i = blockIdx.x * 256 + threadIdx.x;
    if (i < NNZ_E) {
        const int rc = rows[i];
        const int rp = (i == 0) ? -1 : rows[i - 1];   // coalesced re-read, L1 hit
        for (int r = rp + 1; r <= rc; ++r) ptr[r] = i;
        if (i == NNZ_E - 1) {
            for (int r = rc + 1; r <= NN; ++r) ptr[r] = NNZ_E;
        }
    }
    if (i < INF_ * HIDF) {            // W1 [256][128]
        int k = i >> 7, n = i & 127;
        W1t[n * INF_ + k] = f2bf(W1[i]);
    }
    if (i < HIDF * OUTF) {            // W2 [128][64]
        int k = i >> 6, n = i & 63;
        W2t[n * HIDF + k] = f2bf(W2[i]);
    }
}

// ---------------------------------------------------------------------------
// Persistent-block MFMA GEMM (layer 1 only).
// ---------------------------------------------------------------------------
template<int K, int NCOLS, int TR, int CGB, bool A_IS_BF16>
__global__ __launch_bounds__(512, 1) void gemm_persist(const void* __restrict__ Av,
                                                       const unsigned short* __restrict__ Bt,
                                                       const float* __restrict__ bias,
                                                       unsigned short* __restrict__ C,
                                                       int M) {
    constexpr int KS   = K / 32;
    constexpr int NT   = 2;
    constexpr int CG   = 1 << CGB;
    constexpr int RB   = 8 / CG;
    static_assert(RB * 16 == TR, "tile rows = 16*RB");
    static_assert(CG * 32 == NCOLS, "cols = 32*CG");
    constexpr int ABPR = A_IS_BF16 ? K * 2 : K * 4;
    constexpr int RPC  = 1024 / ABPR;
    constexpr int NCH  = TR / RPC;
    constexpr int CPWW = NCH / 8;
    constexpr int ABUF = NCH * 1040;
    constexpr int PK   = K + 8;
    constexpr int PADW = NCOLS + 8;
    constexpr int BSB  = NCOLS * PK * 2;
    constexpr int EPB  = TR * PADW * 2;
    static_assert(TR * NCOLS / 8 == 512, "one uint4 store per thread");
    __shared__ __align__(16) unsigned char smem[2 * ABUF + BSB + EPB];
    unsigned char*  Ab = smem;
    unsigned short* Bs = (unsigned short*)(smem + 2 * ABUF);
    unsigned short* ep = (unsigned short*)(smem + 2 * ABUF + BSB);

    const int tid  = threadIdx.x;
    const int wave = tid >> 6;
    const int lane = tid & 63;
    const int quad = lane >> 4;
    const int l16  = lane & 15;
    const int cg   = wave & (CG - 1);
    const int rb   = wave >> CGB;

    for (int i = tid; i < NCOLS * K / 8; i += 512) {
        int n = i / (K / 8), kc = (i % (K / 8)) * 8;
        *(uint4*)&Bs[n * PK + kc] = *(const uint4*)&Bt[(size_t)n * K + kc];
    }

    const int ntiles = (M + TR - 1) / TR;
    const char* abase = (const char*)Av;

    auto stage = [&](int b, int tile0) {
        unsigned char* dst = Ab + b * ABUF;
        #pragma unroll
        for (int j = 0; j < CPWW; ++j) {
            int ch = wave * CPWW + j;
            int r0 = tile0 + ch * RPC;
            if (r0 > M - RPC) r0 = M - RPC;
            gl2lds16(abase + (size_t)r0 * ABPR + lane * 16, dst + ch * 1040);
        }
    };

    int t = blockIdx.x, buf = 0;
    if (t < ntiles) stage(0, t * TR);

    for (; t < ntiles; t += gridDim.x) {
        __syncthreads();
        int tn = t + gridDim.x;
        if (tn < ntiles) stage(1 - buf, tn * TR);

        const unsigned char* ab = Ab + buf * ABUF;
        const int arow = rb * 16 + l16;
        f32x4 acc[NT];
        #pragma unroll
        for (int tt = 0; tt < NT; ++tt) acc[tt] = (f32x4){0.f, 0.f, 0.f, 0.f};

        #pragma unroll
        for (int ks = 0; ks < KS; ++ks) {
            bf16x8 af;
            if constexpr (A_IS_BF16) {
                int flat = arow * ABPR + ks * 64 + quad * 16;
                af = *(const bf16x8*)(ab + (flat >> 10) * 1040 + (flat & 1023));
            } else {
                int flat = arow * ABPR + ks * 128 + quad * 32;
                const unsigned char* p = ab + (flat >> 10) * 1040 + (flat & 1023);
                float4 a0 = *(const float4*)p;
                float4 a1 = *(const float4*)(p + 16);
                af[0] = (short)f2bf(a0.x); af[1] = (short)f2bf(a0.y);
                af[2] = (short)f2bf(a0.z); af[3] = (short)f2bf(a0.w);
                af[4] = (short)f2bf(a1.x); af[5] = (short)f2bf(a1.y);
                af[6] = (short)f2bf(a1.z); af[7] = (short)f2bf(a1.w);
            }
            #pragma unroll
            for (int tt = 0; tt < NT; ++tt) {
                bf16x8 bfr = *(const bf16x8*)&Bs[(cg * 32 + tt * 16 + l16) * PK + ks * 32 + quad * 8];
                acc[tt] = __builtin_amdgcn_mfma_f32_16x16x32_bf16(af, bfr, acc[tt], 0, 0, 0);
            }
        }

        #pragma unroll
        for (int tt = 0; tt < NT; ++tt) {
            const int col = cg * 32 + tt * 16 + l16;
            const float bb = bias[col];
            #pragma unroll
            for (int r = 0; r < 4; ++r)
                ep[(rb * 16 + quad * 4 + r) * PADW + col] = f2bf(acc[tt][r] + bb);
        }
        __syncthreads();
        {
            constexpr int CH = NCOLS / 8;
            int r = tid / CH, cc = tid % CH;
            int grow = t * TR + r;
            if (grow < M)
                *(uint4*)&C[(size_t)grow * NCOLS + cc * 8] =
                    *(const uint4*)&ep[r * PADW + cc * 8];
        }
        buf ^= 1;
    }
}

// ---------------------------------------------------------------------------
// Shared gather helper (round-0 proven shape).
// ---------------------------------------------------------------------------
__device__ inline void fma8_bf16(float* acc, uint4 q, float v) {
    union { unsigned int i; float f; } t;
    #pragma unroll
    for (int p = 0; p < 4; ++p) {
        unsigned int w = (&q.x)[p];
        t.i = w << 16;          acc[2*p]   += v * t.f;
        t.i = w & 0xffff0000u;  acc[2*p+1] += v * t.f;
    }
}

template<int D>
__device__ inline void spmm_row_accum(int e, int e1,
                                      const int* __restrict__ cols,
                                      const float* __restrict__ vals,
                                      const unsigned short* __restrict__ dense,
                                      size_t lo8, float* acc) {
    if (e >= e1) return;
    for (; e + 4 <= e1; e += 4) {
        int   c0 = cols[e],   c1 = cols[e+1], c2 = cols[e+2], c3 = cols[e+3];
        float v0 = vals[e],   v1 = vals[e+1], v2 = vals[e+2], v3 = vals[e+3];
        uint4 q0 = *(const uint4*)&dense[(size_t)c0 * D + lo8];
        uint4 q1 = *(const uint4*)&dense[(size_t)c1 * D + lo8];
        uint4 q2 = *(const uint4*)&dense[(size_t)c2 * D + lo8];
        uint4 q3 = *(const uint4*)&dense[(size_t)c3 * D + lo8];
        fma8_bf16(acc, q0, v0);
        fma8_bf16(acc, q1, v1);
        fma8_bf16(acc, q2, v2);
        fma8_bf16(acc, q3, v3);
    }
    if (e < e1) {   // padded final batch: clamp index, zero value
        int i1 = e, i2 = e + 1, i3 = e + 2;
        bool k1 = i1 < e1, k2 = i2 < e1, k3 = i3 < e1;
        i1 = k1 ? i1 : e1 - 1; i2 = k2 ? i2 : e1 - 1; i3 = k3 ? i3 : e1 - 1;
        int   c0 = cols[i1],            c1 = cols[i2],            c2 = cols[i3];
        float v0 = k1 ? vals[i1] : 0.f, v1 = k2 ? vals[i2] : 0.f, v2 = k3 ? vals[i3] : 0.f;
        uint4 q0 = *(const uint4*)&dense[(size_t)c0 * D + lo8];
        uint4 q1 = *(const uint4*)&dense[(size_t)c1 * D + lo8];
        uint4 q2 = *(const uint4*)&dense[(size_t)c2 * D + lo8];
        fma8_bf16(acc, q0, v0);
        fma8_bf16(acc, q1, v1);
        fma8_bf16(acc, q2, v2);
    }
}

// ---------------------------------------------------------------------------
// FUSED: h = relu(spmm(h0)); z0 = h @ W2 + b2  -> bf16 [N,64], one kernel.
// Block = 256 threads = 16 rows x 16 lanes (D=128 gather, round-0 shape).
// Epilogue: stage 16x128 h-tile + padded W2 in LDS, 4 waves x 4 MFMAs
// produce the 16x64 z0 tile. Eliminates gemm2's dispatch + 38.4 MB traffic
// and halves this kernel's write (25.6 -> 12.8 MB).
// Rows with no edges naturally yield z0 = b2 (h row = 0), same as unfused.
// ---------------------------------------------------------------------------
__global__ __launch_bounds__(256) void spmm1_fused(const int* __restrict__ ptr,
                                                   const int* __restrict__ cols,
                                                   const float* __restrict__ vals,
                                                   const unsigned short* __restrict__ dense, // h0 [N,128]
                                                   const unsigned short* __restrict__ W2t,   // [64][128]
                                                   const float* __restrict__ b2,
                                                   unsigned short* __restrict__ z0) {        // [N,64]
    constexpr int D = 128;
    static_assert(NN % 16 == 0, "exact tiling, no tail guard");
    // padded rows (+8 elems = 16B) -> MFMA b128 LDS reads are ~2-way, free
    __shared__ __align__(16) unsigned short W2s[64 * 136];
    __shared__ __align__(16) unsigned short ht[16 * 136];
    __shared__ __align__(16) unsigned short zt[16 * 72];

    const int tid = threadIdx.x;

    // stage W2 into padded LDS (16 KB from L2; hot after first blocks)
    #pragma unroll
    for (int i = 0; i < 4; ++i) {
        int idx = tid + i * 256;            // 1024 uint4 chunks total
        int r = idx >> 4, ch = idx & 15;
        *(uint4*)&W2s[r * 136 + ch * 8] = *(const uint4*)&W2t[r * 128 + ch * 8];
    }

    // ---- gather phase (identical inner loop to round-0 spmm) ----
    const int lane16 = tid & 15;
    const int rl     = tid >> 4;
    const int row    = blockIdx.x * 16 + rl;
    const size_t lo8 = (size_t)lane16 * 8;
    float acc[8] = {};
    spmm_row_accum<D>(ptr[row], ptr[row + 1], cols, vals, dense, lo8, acc);

    uint4 o;
    #pragma unroll
    for (int p = 0; p < 4; ++p) {
        float a0 = fmaxf(acc[2*p],   0.f);
        float a1 = fmaxf(acc[2*p+1], 0.f);
        (&o.x)[p] = (unsigned int)f2bf(a0) | ((unsigned int)f2bf(a1) << 16);
    }
    *(uint4*)&ht[rl * 136 + lane16 * 8] = o;
    __syncthreads();

    // ---- MFMA epilogue: z0 tile = ht(16x128) @ W2(128x64) ----
    const int wv   = tid >> 6;       // wave -> output col block wv*16
    const int lane = tid & 63;
    const int l16  = lane & 15;
    const int quad = lane >> 4;
    f32x4 c = (f32x4){0.f, 0.f, 0.f, 0.f};
    #pragma unroll
    for (int ks = 0; ks < 4; ++ks) {
        bf16x8 af = *(const bf16x8*)&ht[l16 * 136 + ks * 32 + quad * 8];
        bf16x8 bf_ = *(const bf16x8*)&W2s[(wv * 16 + l16) * 136 + ks * 32 + quad * 8];
        c = __builtin_amdgcn_mfma_f32_16x16x32_bf16(af, bf_, c, 0, 0, 0);
    }
    const float bb = b2[wv * 16 + l16];
    #pragma unroll
    for (int r = 0; r < 4; ++r)
        zt[(quad * 4 + r) * 72 + wv * 16 + l16] = f2bf(c[r] + bb);
    __syncthreads();

    // coalesced store: 16 rows x 64 cols bf16 = 128 uint4
    if (tid < 128) {
        int r = tid >> 3, cc = tid & 7;
        *(uint4*)&z0[((size_t)blockIdx.x * 16 + r) * 64 + cc * 8] =
            *(const uint4*)&zt[r * 72 + cc * 8];
    }
}

// ---------------------------------------------------------------------------
// Plain SpMM (layer 2, D=64): round-0 proven kernel.
// ---------------------------------------------------------------------------
template<int D, bool RELU>
__global__ __launch_bounds__(256) void spmm_bf16(const int* __restrict__ ptr,
                                                 const int* __restrict__ cols,
                                                 const float* __restrict__ vals,
                                                 const unsigned short* __restrict__ dense,
                                                 unsigned short* __restrict__ outm) {
    constexpr int LPR = D / 8;       // lanes per row
    constexpr int RPB = 256 / LPR;   // rows per block
    const int lane = threadIdx.x % LPR;
    const int row  = blockIdx.x * RPB + threadIdx.x / LPR;
    if (row >= NN) return;

    const size_t lo8 = (size_t)lane * 8;
    float acc[8] = {};
    spmm_row_accum<D>(ptr[row], ptr[row + 1], cols, vals, dense, lo8, acc);

    if (RELU) {
        #pragma unroll
        for (int p = 0; p < 8; ++p) acc[p] = fmaxf(acc[p], 0.f);
    }
    uint4 o;
    #pragma unroll
    for (int p = 0; p < 4; ++p)
        (&o.x)[p] = (unsigned int)f2bf(acc[2*p]) | ((unsigned int)f2bf(acc[2*p+1]) << 16);
    *(uint4*)&outm[(size_t)row * D + lo8] = o;
}

// ---------------------------------------------------------------------------
// Decode: out[e] = dot(z[src[e]], z[dst[e]]), z bf16 [N,64]. 8 lanes/edge,
// 2 edges per lane-group -> 4 independent gathers in flight.
// ---------------------------------------------------------------------------
__global__ __launch_bounds__(256) void decode_dot_bf16(const unsigned short* __restrict__ z,
                                                       const int* __restrict__ ei,
                                                       float* __restrict__ outv) {
    constexpr int HALF = EQn / 2;
    const int lane = threadIdx.x & 7;
    const int g    = blockIdx.x * 32 + (threadIdx.x >> 3);
    if (g >= HALF) return;
    const int eA = g, eB = g + HALF;
    const int sA = ei[eA],       dA = ei[EQn + eA];
    const int sB = ei[eB],       dB = ei[EQn + eB];
    uint4 qa0 = *(const uint4*)&z[(size_t)sA * 64 + lane * 8];
    uint4 qb0 = *(const uint4*)&z[(size_t)dA * 64 + lane * 8];
    uint4 qa1 = *(const uint4*)&z[(size_t)sB * 64 + lane * 8];
    uint4 qb1 = *(const uint4*)&z[(size_t)dB * 64 + lane * 8];
    union { unsigned int i; float f; } ta, tb;
    float p0 = 0.f, p1 = 0.f;
    #pragma unroll
    for (int k = 0; k < 4; ++k) {
        unsigned int wa = (&qa0.x)[k], wb = (&qb0.x)[k];
        ta.i = wa << 16;         tb.i = wb << 16;         p0 += ta.f * tb.f;
        ta.i = wa & 0xffff0000u; tb.i = wb & 0xffff0000u; p0 += ta.f * tb.f;
        wa = (&qa1.x)[k]; wb = (&qb1.x)[k];
        ta.i = wa << 16;         tb.i = wb << 16;         p1 += ta.f * tb.f;
        ta.i = wa & 0xffff0000u; tb.i = wb & 0xffff0000u; p1 += ta.f * tb.f;
    }
    p0 += __shfl_xor(p0, 1, 8); p1 += __shfl_xor(p1, 1, 8);
    p0 += __shfl_xor(p0, 2, 8); p1 += __shfl_xor(p1, 2, 8);
    p0 += __shfl_xor(p0, 4, 8); p1 += __shfl_xor(p1, 4, 8);
    if (lane == 0) { outv[eA] = p0; outv[eB] = p1; }
}

// ---------------------------------------------------------------------------
extern "C" void kernel_launch(void* const* d_in, const int* in_sizes, int n_in,
                              void* d_out, int out_size, void* d_ws, size_t ws_size,
                              hipStream_t stream) {
    (void)in_sizes; (void)n_in; (void)out_size; (void)ws_size;

    const float* x        = (const float*)d_in[0];
    const int*   adj_rows = (const int*)  d_in[1];
    const int*   adj_cols = (const int*)  d_in[2];
    const float* adj_vals = (const float*)d_in[3];
    const int*   ei       = (const int*)  d_in[4];   // [2, EQ]
    const float* W1       = (const float*)d_in[5];
    const float* b1       = (const float*)d_in[6];
    const float* W2       = (const float*)d_in[7];
    const float* b2       = (const float*)d_in[8];
    float* out = (float*)d_out;

    // workspace: row_ptr | W1t | W2t | slotA bf16 [N,128] | slotB bf16 [N,128]
    char* ws = (char*)d_ws;
    int* row_ptr = (int*)ws;
    size_t off = ((size_t)(NN + 1) * sizeof(int) + 511) & ~(size_t)511;
    unsigned short* W1t = (unsigned short*)(ws + off);              // 64 KB
    unsigned short* W2t = W1t + (size_t)HIDF * INF_;                // 16 KB
    unsigned short* slotA = W2t + (size_t)OUTF * HIDF;
    slotA = (unsigned short*)(((size_t)slotA + 511) & ~(size_t)511);
    unsigned short* slotB = slotA + (size_t)NN * HIDF;

    // prep v2: boundary-scan row_ptr (grid covers all NNZ edges)
    prep<<<(NNZ_E + 255) / 256, 256, 0, stream>>>(adj_rows, row_ptr, W1, W2, W1t, W2t);

    // h0 = x @ W1 + b1  -> slotA bf16 [N,128]   (persistent: ~1 block/CU)
    gemm_persist<INF_, HIDF, 32, 2, false><<<256, 512, 0, stream>>>(
        x, W1t, b1, slotA, NN);

    // z0 = relu(spmm(h0)) @ W2 + b2 -> slotB bf16 [N,64]   (FUSED)
    spmm1_fused<<<NN / 16, 256, 0, stream>>>(
        row_ptr, adj_cols, adj_vals, slotA, W2t, b2, slotB);

    // z = spmm(z0) -> slotA bf16 [N,64]
    spmm_bf16<OUTF, false><<<(NN + 31) / 32, 256, 0, stream>>>(
        row_ptr, adj_cols, adj_vals, slotB, slotA);

    // out[e] = dot(z[src], z[dst])
    decode_dot_bf16<<<(EQn / 2) / 32, 256, 0, stream>>>(slotA, ei, out);
}